// Round 2
// baseline (115.357 us; speedup 1.0000x reference)
//
#include <hip/hip_runtime.h>
#include <math.h>

// Problem constants: B=32, S=4096, H=768.
constexpr int B = 32;
constexpr int S = 4096;
constexpr int H = 768;

constexpr int BPB            = 32;             // partial blocks per batch
constexpr int ROWS_PER_BLOCK = S / BPB;        // 128
constexpr int ROWS_PER_WAVE  = ROWS_PER_BLOCK / 4; // 32
constexpr int NPART          = B * BPB;        // 1024

// ---------------------------------------------------------------------------
// Kernel 1: fused score + online-softmax pooling, one streaming pass.
// Each wave = two 32-lane groups, each group owns one row per iteration
// (2 rows/iter/wave). Lane k of a group owns columns {4k..4k+3} + 128*j.
// Explicit 1-deep prefetch keeps loads in flight during the reduce chain.
// ---------------------------------------------------------------------------
__global__ __launch_bounds__(256, 4)
void pool_partial(const float* __restrict__ hs,
                  const int*   __restrict__ mask,
                  const int*   __restrict__ boost,
                  const float* __restrict__ attn_w,
                  const float* __restrict__ attn_b,
                  float* __restrict__ pm, float* __restrict__ pl,
                  float* __restrict__ pc)
{
    const int blk  = blockIdx.x;                 // 0..1023
    const int b    = blk >> 5;                   // batch
    const int kb   = blk & (BPB - 1);
    const int tid  = threadIdx.x;
    const int w    = tid >> 6;                   // wave id in block
    const int lane = tid & 63;
    const int g    = lane >> 5;                  // group 0/1
    const int k    = lane & 31;                  // lane within group

    // attention weights: lane k owns columns 4k + 128*j, j = 0..5
    float4 wv[6];
#pragma unroll
    for (int j = 0; j < 6; ++j)
        wv[j] = *reinterpret_cast<const float4*>(attn_w + 128 * j + 4 * k);
    const float bias = attn_b[0];

    const int s0 = kb * ROWS_PER_BLOCK + w * ROWS_PER_WAVE;
    const float* base = hs + (size_t)b * S * H;

    // per-lane row meta for row s0+(lane&31): mult==0 encodes masked-out
    {
    }
    const int   srl   = s0 + (lane & 31);
    const int   mk0   = mask[(size_t)b * S + srl];
    const float mult0 = mk0 ? (1.0f + 2.0f * (float)boost[(size_t)b * S + srl]) : 0.0f;

    float m = -INFINITY, l = 0.0f;
    float4 c[6];
#pragma unroll
    for (int j = 0; j < 6; ++j) c[j] = make_float4(0.f, 0.f, 0.f, 0.f);

    // prefetch first rows (group g handles row s0 + 2*i + g)
    const float* rp = base + (size_t)(s0 + g) * H + 4 * k;
    float4 v[6];
#pragma unroll
    for (int j = 0; j < 6; ++j)
        v[j] = *reinterpret_cast<const float4*>(rp + 128 * j);

    for (int i = 0; i < ROWS_PER_WAVE / 2; ++i) {
        // prefetch next pair of rows
        float4 vn[6];
        const float* rn = rp + 2 * H;
        if (i + 1 < ROWS_PER_WAVE / 2) {
#pragma unroll
            for (int j = 0; j < 6; ++j)
                vn[j] = *reinterpret_cast<const float4*>(rn + 128 * j);
        }

        // partial dot, 4 independent chains
        float d0 = 0.f, d1 = 0.f, d2 = 0.f, d3 = 0.f;
#pragma unroll
        for (int j = 0; j < 6; ++j) {
            d0 = fmaf(v[j].x, wv[j].x, d0);
            d1 = fmaf(v[j].y, wv[j].y, d1);
            d2 = fmaf(v[j].z, wv[j].z, d2);
            d3 = fmaf(v[j].w, wv[j].w, d3);
        }
        float d = (d0 + d1) + (d2 + d3);

        // reduce within the 32-lane group
#pragma unroll
        for (int off = 16; off >= 1; off >>= 1)
            d += __shfl_xor(d, off, 64);

        const float mult  = __shfl(mult0, 2 * i + g, 64);
        const float score = (d + bias) * mult;

        if (mult > 0.0f) {
            if (score <= m) {                      // common path: no rescale
                const float p = __expf(score - m);
                l += p;
#pragma unroll
                for (int j = 0; j < 6; ++j) {
                    c[j].x = fmaf(p, v[j].x, c[j].x);
                    c[j].y = fmaf(p, v[j].y, c[j].y);
                    c[j].z = fmaf(p, v[j].z, c[j].z);
                    c[j].w = fmaf(p, v[j].w, c[j].w);
                }
            } else {                               // new max: rescale
                const float sc = __expf(m - score); // 0 when m == -inf
                m = score;
                l = fmaf(l, sc, 1.0f);
#pragma unroll
                for (int j = 0; j < 6; ++j) {
                    c[j].x = fmaf(c[j].x, sc, v[j].x);
                    c[j].y = fmaf(c[j].y, sc, v[j].y);
                    c[j].z = fmaf(c[j].z, sc, v[j].z);
                    c[j].w = fmaf(c[j].w, sc, v[j].w);
                }
            }
        }
#pragma unroll
        for (int j = 0; j < 6; ++j) v[j] = vn[j];
        rp = rn;
    }

    // fold group 1 into group 0 (common max across the two groups)
    const float mo = __shfl_xor(m, 32, 64);
    const float M2 = fmaxf(m, mo);
    const float e  = (l > 0.0f) ? __expf(m - M2) : 0.0f;
    float l2 = l * e;
    l2 += __shfl_xor(l2, 32, 64);
#pragma unroll
    for (int j = 0; j < 6; ++j) {
        c[j].x *= e; c[j].y *= e; c[j].z *= e; c[j].w *= e;
        c[j].x += __shfl_xor(c[j].x, 32, 64);
        c[j].y += __shfl_xor(c[j].y, 32, 64);
        c[j].z += __shfl_xor(c[j].z, 32, 64);
        c[j].w += __shfl_xor(c[j].w, 32, 64);
    }

    // intra-block combine (4 waves -> 1 partial)
    __shared__ float sm[4], sl[4];
    __shared__ float scmb[4][H];
    if (g == 0) {
        if (k == 0) { sm[w] = M2; sl[w] = l2; }
#pragma unroll
        for (int j = 0; j < 6; ++j)
            *reinterpret_cast<float4*>(&scmb[w][128 * j + 4 * k]) = c[j];
    }
    __syncthreads();

    const float M  = fmaxf(fmaxf(sm[0], sm[1]), fmaxf(sm[2], sm[3]));
    const float e0 = (sl[0] > 0.f) ? __expf(sm[0] - M) : 0.f;
    const float e1 = (sl[1] > 0.f) ? __expf(sm[1] - M) : 0.f;
    const float e2 = (sl[2] > 0.f) ? __expf(sm[2] - M) : 0.f;
    const float e3 = (sl[3] > 0.f) ? __expf(sm[3] - M) : 0.f;
    if (tid == 0) {
        pm[blk] = M;
        pl[blk] = sl[0] * e0 + sl[1] * e1 + sl[2] * e2 + sl[3] * e3;
    }
#pragma unroll
    for (int q = 0; q < 3; ++q) {
        const int h = tid + q * 256;
        pc[(size_t)blk * H + h] =
            scmb[0][h] * e0 + scmb[1][h] * e1 + scmb[2][h] * e2 + scmb[3][h] * e3;
    }
}

// ---------------------------------------------------------------------------
// Kernel 2: combine 32 partials per batch -> context[32][768].
// Grid (3, 32): one block per (column-chunk, batch) so the 3 MB read is
// spread over 96 CUs.
// ---------------------------------------------------------------------------
__global__ __launch_bounds__(256)
void pool_combine(const float* __restrict__ pm, const float* __restrict__ pl,
                  const float* __restrict__ pc, float* __restrict__ context)
{
    const int qc  = blockIdx.x;
    const int b   = blockIdx.y;
    const int tid = threadIdx.x;
    __shared__ float ss[BPB];
    __shared__ float sinv;

    if (tid < BPB) {
        const float mv = pm[b * BPB + tid];
        float M = mv;
#pragma unroll
        for (int off = 16; off >= 1; off >>= 1)
            M = fmaxf(M, __shfl_xor(M, off, 64));
        const float e = __expf(mv - M);
        ss[tid] = e;
        float lv = pl[b * BPB + tid] * e;
#pragma unroll
        for (int off = 16; off >= 1; off >>= 1)
            lv += __shfl_xor(lv, off, 64);
        if (tid == 0) sinv = 1.0f / lv;
    }
    __syncthreads();

    const int h = qc * 256 + tid;
    float acc = 0.0f;
#pragma unroll 4
    for (int i = 0; i < BPB; ++i)
        acc = fmaf(pc[((size_t)b * BPB + i) * H + h], ss[i], acc);
    context[b * H + h] = acc * sinv;
}

// ---------------------------------------------------------------------------
// Kernel 3: BatchNorm1d (batch stats, biased variance, eps=1e-5)
// ---------------------------------------------------------------------------
__global__ __launch_bounds__(256)
void batchnorm_k(const float* __restrict__ context,
                 const float* __restrict__ gamma, const float* __restrict__ beta,
                 float* __restrict__ chat)
{
    const int h = blockIdx.x * 256 + threadIdx.x;  // 0..767
    float x[B];
    float mean = 0.0f;
#pragma unroll
    for (int b = 0; b < B; ++b) { x[b] = context[b * H + h]; mean += x[b]; }
    mean *= (1.0f / B);
    float var = 0.0f;
#pragma unroll
    for (int b = 0; b < B; ++b) { const float d = x[b] - mean; var += d * d; }
    var *= (1.0f / B);
    const float inv = rsqrtf(var + 1e-5f);
    const float gq = gamma[h], be = beta[h];
#pragma unroll
    for (int b = 0; b < B; ++b)
        chat[b * H + h] = (x[b] - mean) * inv * gq + be;
}

// ---------------------------------------------------------------------------
// Kernel 4: out = relu(chat @ fc_w.T + fc_b + chat)
// ---------------------------------------------------------------------------
__global__ __launch_bounds__(256)
void fc_relu_k(const float* __restrict__ chat, const float* __restrict__ fcw,
               const float* __restrict__ fcb, float* __restrict__ out)
{
    const int i = blockIdx.x * 256 + threadIdx.x;  // output column
    const int b = blockIdx.y;                      // batch row
    const float* cb = chat + (size_t)b * H;
    const float4* wr  = reinterpret_cast<const float4*>(fcw + (size_t)i * H);
    const float4* cbv = reinterpret_cast<const float4*>(cb);

    float acc = fcb[i];
#pragma unroll 4
    for (int hq = 0; hq < H / 4; ++hq) {
        const float4 wvv = wr[hq];
        const float4 cv  = cbv[hq];
        acc += wvv.x * cv.x + wvv.y * cv.y + wvv.z * cv.z + wvv.w * cv.w;
    }
    acc += cb[i];
    out[(size_t)b * H + i] = fmaxf(acc, 0.0f);
}

// ---------------------------------------------------------------------------
extern "C" void kernel_launch(void* const* d_in, const int* in_sizes, int n_in,
                              void* d_out, int out_size, void* d_ws, size_t ws_size,
                              hipStream_t stream)
{
    const float* hs     = (const float*)d_in[0];
    const int*   mask   = (const int*)d_in[1];
    const int*   boost  = (const int*)d_in[2];
    const float* attn_w = (const float*)d_in[3];
    const float* attn_b = (const float*)d_in[4];
    const float* fc_w   = (const float*)d_in[5];
    const float* fc_b   = (const float*)d_in[6];
    const float* gamma  = (const float*)d_in[7];
    const float* beta   = (const float*)d_in[8];
    float* out = (float*)d_out;

    float* ws      = (float*)d_ws;
    float* pm      = ws;                          // [1024]
    float* pl      = pm + NPART;                  // [1024]
    float* pc      = pl + NPART;                  // [1024][768]
    float* context = pc + (size_t)NPART * H;      // [32][768]
    float* chat    = context + B * H;             // [32][768]
    // total: ~3.35 MB of d_ws

    pool_partial<<<dim3(NPART), 256, 0, stream>>>(hs, mask, boost, attn_w, attn_b,
                                                  pm, pl, pc);
    pool_combine<<<dim3(H / 256, B), 256, 0, stream>>>(pm, pl, pc, context);
    batchnorm_k<<<dim3(H / 256), 256, 0, stream>>>(context, gamma, beta, chat);
    fc_relu_k<<<dim3(H / 256, B), 256, 0, stream>>>(chat, fc_w, fc_b, out);
}